// Round 1
// baseline (433.631 us; speedup 1.0000x reference)
//
#include <hip/hip_runtime.h>

#define NDET 5000
#define NCLS 80
#define DSTR 84      // 4 box coords + 80 class scores
#define TOPK 1000
#define CROP 14
#define NPIX (CROP * CROP)   // 196
#define C    256

// ---------------- Phase 1a: per-detection score = max over classes ----------
__global__ void scores_kernel(const float* __restrict__ det, float* __restrict__ scores) {
    int i = blockIdx.x * blockDim.x + threadIdx.x;
    if (i >= NDET) return;
    const float* row = det + i * DSTR + 4;
    float m = row[0];
    #pragma unroll
    for (int c = 1; c < NCLS; ++c) m = fmaxf(m, row[c]);
    scores[i] = m;
}

// ---------------- Phase 1b: exact top-k by rank counting --------------------
// rank(i) = #{j : s_j > s_i} + #{j < i : s_j == s_i}
// Matches jax.lax.top_k ordering (descending value, ties -> lower index).
__global__ void topk_kernel(const float* __restrict__ scores, int* __restrict__ topk_idx) {
    __shared__ float s[NDET];           // 20000 B
    for (int j = threadIdx.x; j < NDET; j += blockDim.x) s[j] = scores[j];
    __syncthreads();
    int i = blockIdx.x * blockDim.x + threadIdx.x;
    if (i >= NDET) return;
    float my = s[i];
    int rank = 0;
    for (int j = 0; j < NDET; ++j) {
        float v = s[j];
        rank += (v > my) | ((v == my) & (j < i));
    }
    if (rank < TOPK) topk_idx[rank] = i;
}

// ---------------- Phase 1c: levels + stable sort by level -------------------
// pos(r) = #{s : L_s < L_r} + #{s < r : L_s == L_r}  (stable argsort on levels)
__global__ void order_kernel(const float* __restrict__ det, const int* __restrict__ topk_idx,
                             int* __restrict__ slot_det, int* __restrict__ slot_level) {
    __shared__ int lvl[TOPK];
    int r = threadIdx.x;
    int di = 0, L = 0;
    if (r < TOPK) {
        di = topk_idx[r];
        const float* b = det + di * DSTR;
        float w = b[2] - b[0];
        float h = b[3] - b[1];
        float sz = sqrtf(w * h);
        float lf = floorf(1.0f + log2f(sz / 224.0f + 1e-7f));
        lf = fminf(fmaxf(lf, 0.0f), 4.0f);
        L = (int)lf;
        lvl[r] = L;
    }
    __syncthreads();
    if (r < TOPK) {
        int pos = 0;
        for (int s = 0; s < TOPK; ++s) {
            int Ls = lvl[s];
            pos += (Ls < L) | ((Ls == L) & (s < r));
        }
        slot_det[pos] = di;
        slot_level[pos] = L;
    }
}

// ---------------- Phase 2: crop_and_resize main kernel ----------------------
// One wave (64 lanes) per output pixel; lane handles 4 contiguous channels
// (float4). Block = 256 threads = 4 pixels; 49 blocks per box.
__device__ __forceinline__ float blerp(float f00, float f01, float f10, float f11,
                                       float lx, float ly) {
    float top = f00 + (f01 - f00) * lx;
    float bot = f10 + (f11 - f10) * lx;
    return top + (bot - top) * ly;
}

__global__ __launch_bounds__(256) void crop_kernel(
    const float* __restrict__ det,
    const float* __restrict__ p0, const float* __restrict__ p1,
    const float* __restrict__ p2, const float* __restrict__ p3,
    const float* __restrict__ p4,
    const int* __restrict__ slot_det, const int* __restrict__ slot_level,
    float* __restrict__ out)
{
    int wave = threadIdx.x >> 6;
    int lane = threadIdx.x & 63;
    int slot = blockIdx.x / 49;
    int p    = (blockIdx.x % 49) * 4 + wave;   // pixel index 0..195
    int py = p / CROP, px = p % CROP;

    int di = slot_det[slot];
    int L  = slot_level[slot];

    const float* feat; int H;
    switch (L) {
        case 0:  feat = p0; H = 256; break;
        case 1:  feat = p1; H = 128; break;
        case 2:  feat = p2; H = 64;  break;
        case 3:  feat = p3; H = 32;  break;
        default: feat = p4; H = 16;  break;
    }
    float hf = (float)(H - 1);

    const float* b = det + di * DSTR;
    float bx1 = b[0], by1 = b[1], bx2 = b[2], by2 = b[3];

    // Reference: boxes = [y1/hf, x1/wf, y2/hf, x2/wf]; ys = (b0 + (b2-b0)*ty)*hf
    float y1n = by1 / hf, y2n = by2 / hf;
    float x1n = bx1 / hf, x2n = bx2 / hf;   // W == H per level
    float ty = (float)py / 13.0f;
    float tx = (float)px / 13.0f;
    float ys = (y1n + (y2n - y1n) * ty) * hf;
    float xs = (x1n + (x2n - x1n) * tx) * hf;

    float4* outp = (float4*)(out + (size_t)(slot * NPIX + p) * C) + lane;

    bool valid = (ys >= 0.0f) & (ys <= hf) & (xs >= 0.0f) & (xs <= hf);
    if (!valid) {
        *outp = make_float4(0.0f, 0.0f, 0.0f, 0.0f);
        return;
    }

    float y0f = floorf(ys), x0f = floorf(xs);
    float ly = ys - y0f,    lx = xs - x0f;
    int y0i = (int)fminf(fmaxf(y0f,        0.0f), hf);
    int y1i = (int)fminf(fmaxf(y0f + 1.0f, 0.0f), hf);
    int x0i = (int)fminf(fmaxf(x0f,        0.0f), hf);
    int x1i = (int)fminf(fmaxf(x0f + 1.0f, 0.0f), hf);

    const float4* f00 = (const float4*)(feat + (size_t)(y0i * H + x0i) * C) + lane;
    const float4* f01 = (const float4*)(feat + (size_t)(y0i * H + x1i) * C) + lane;
    const float4* f10 = (const float4*)(feat + (size_t)(y1i * H + x0i) * C) + lane;
    const float4* f11 = (const float4*)(feat + (size_t)(y1i * H + x1i) * C) + lane;

    float4 a = *f00, c01 = *f01, d10 = *f10, e11 = *f11;
    float4 o;
    o.x = blerp(a.x, c01.x, d10.x, e11.x, lx, ly);
    o.y = blerp(a.y, c01.y, d10.y, e11.y, lx, ly);
    o.z = blerp(a.z, c01.z, d10.z, e11.z, lx, ly);
    o.w = blerp(a.w, c01.w, d10.w, e11.w, lx, ly);
    *outp = o;
}

extern "C" void kernel_launch(void* const* d_in, const int* in_sizes, int n_in,
                              void* d_out, int out_size, void* d_ws, size_t ws_size,
                              hipStream_t stream) {
    const float* det = (const float*)d_in[0];
    const float* p0  = (const float*)d_in[1];
    const float* p1  = (const float*)d_in[2];
    const float* p2  = (const float*)d_in[3];
    const float* p3  = (const float*)d_in[4];
    const float* p4  = (const float*)d_in[5];
    float* out = (float*)d_out;

    char* ws = (char*)d_ws;
    float* scores    = (float*)(ws + 0);          // 5000 floats
    int*   topk_idx  = (int*)(ws + 20000);        // 1000 ints
    int*   slot_det  = (int*)(ws + 24000);        // 1000 ints
    int*   slot_lvl  = (int*)(ws + 28000);        // 1000 ints

    scores_kernel<<<(NDET + 255) / 256, 256, 0, stream>>>(det, scores);
    topk_kernel<<<(NDET + 255) / 256, 256, 0, stream>>>(scores, topk_idx);
    order_kernel<<<1, 1024, 0, stream>>>(det, topk_idx, slot_det, slot_lvl);
    crop_kernel<<<TOPK * (NPIX / 4), 256, 0, stream>>>(det, p0, p1, p2, p3, p4,
                                                       slot_det, slot_lvl, out);
}

// Round 2
// 282.429 us; speedup vs baseline: 1.5354x; 1.5354x over previous
//
#include <hip/hip_runtime.h>

#define NDET 5000
#define NCLS 80
#define DSTR 84      // 4 box coords + 80 class scores
#define TOPK 1000
#define CROP 14
#define NPIX (CROP * CROP)   // 196
#define C    256

#define JCHUNK 250           // 5000 / 20 j-chunks
#define ICHUNK 256

// ---------------- Phase 1a: scores + zero the rank array --------------------
__global__ void scores_kernel(const float* __restrict__ det, float* __restrict__ scores,
                              int* __restrict__ rank) {
    int i = blockIdx.x * blockDim.x + threadIdx.x;
    if (i >= NDET) return;
    const float* row = det + i * DSTR + 4;
    float m = row[0];
    #pragma unroll
    for (int c = 1; c < NCLS; ++c) m = fmaxf(m, row[c]);
    scores[i] = m;
    rank[i] = 0;
}

// ---------------- Phase 1b: distributed rank counting -----------------------
// rank(i) = #{j : s_j > s_i} + #{j < i : s_j == s_i}   (jax.lax.top_k order)
// Grid: x = i-chunk (20 x 256 threads), y = j-chunk (20 x 250 elements).
__global__ __launch_bounds__(ICHUNK) void rank_kernel(const float* __restrict__ scores,
                                                      int* __restrict__ rank) {
    __shared__ float s[JCHUNK];
    int jbase = blockIdx.y * JCHUNK;
    for (int t = threadIdx.x; t < JCHUNK; t += blockDim.x) s[t] = scores[jbase + t];
    __syncthreads();
    int i = blockIdx.x * ICHUNK + threadIdx.x;
    if (i >= NDET) return;
    float my = scores[i];
    int r = 0;
    #pragma unroll 5
    for (int t = 0; t < JCHUNK; ++t) {
        float v = s[t];
        int j = jbase + t;
        r += (v > my) | ((v == my) & (j < i));
    }
    atomicAdd(&rank[i], r);
}

__global__ void scatter_kernel(const int* __restrict__ rank, int* __restrict__ topk_idx) {
    int i = blockIdx.x * blockDim.x + threadIdx.x;
    if (i >= NDET) return;
    int r = rank[i];
    if (r < TOPK) topk_idx[r] = i;
}

// ---------------- Phase 1c: levels + stable counting-sort via packed scan ---
// key(r) = 1 << 12*L  (5 levels, counts < 4096). Exclusive prefix over 1000
// elements gives stable within-level position; grand total gives level bases.
__global__ __launch_bounds__(1024) void order_kernel(const float* __restrict__ det,
                                                     const int* __restrict__ topk_idx,
                                                     int* __restrict__ slot_det,
                                                     int* __restrict__ slot_level) {
    __shared__ unsigned long long wave_tot[16];
    int r = threadIdx.x;
    int di = 0, L = 0;
    unsigned long long key = 0;
    if (r < TOPK) {
        di = topk_idx[r];
        const float* b = det + di * DSTR;
        float w = b[2] - b[0];
        float h = b[3] - b[1];
        float sz = sqrtf(w * h);
        float lf = floorf(1.0f + log2f(sz / 224.0f + 1e-7f));
        lf = fminf(fmaxf(lf, 0.0f), 4.0f);
        L = (int)lf;
        key = 1ULL << (12 * L);
    }
    // wave-level inclusive scan (64 lanes)
    unsigned long long incl = key;
    #pragma unroll
    for (int d = 1; d < 64; d <<= 1) {
        unsigned long long up = __shfl_up(incl, d, 64);
        if ((r & 63) >= d) incl += up;
    }
    int wave = r >> 6;
    if ((r & 63) == 63) wave_tot[wave] = incl;
    __syncthreads();
    unsigned long long waveoff = 0, total = 0;
    for (int w = 0; w < 16; ++w) {
        unsigned long long t = wave_tot[w];
        if (w < wave) waveoff += t;
        total += t;
    }
    if (r < TOPK) {
        unsigned long long excl = waveoff + incl - key;
        int base = 0;
        for (int l = 0; l < L; ++l) base += (int)((total >> (12 * l)) & 0xFFF);
        int within = (int)((excl >> (12 * L)) & 0xFFF);
        int pos = base + within;
        slot_det[pos] = di;
        slot_level[pos] = L;
    }
}

// ---------------- Phase 2: crop_and_resize main kernel ----------------------
__device__ __forceinline__ float blerp(float f00, float f01, float f10, float f11,
                                       float lx, float ly) {
    float top = f00 + (f01 - f00) * lx;
    float bot = f10 + (f11 - f10) * lx;
    return top + (bot - top) * ly;
}

__global__ __launch_bounds__(256) void crop_kernel(
    const float* __restrict__ det,
    const float* __restrict__ p0, const float* __restrict__ p1,
    const float* __restrict__ p2, const float* __restrict__ p3,
    const float* __restrict__ p4,
    const int* __restrict__ slot_det, const int* __restrict__ slot_level,
    float* __restrict__ out)
{
    int wave = threadIdx.x >> 6;
    int lane = threadIdx.x & 63;
    int slot = blockIdx.x / 49;
    int p    = (blockIdx.x % 49) * 4 + wave;   // pixel index 0..195
    int py = p / CROP, px = p % CROP;

    int di = slot_det[slot];
    int L  = slot_level[slot];

    const float* feat; int H;
    switch (L) {
        case 0:  feat = p0; H = 256; break;
        case 1:  feat = p1; H = 128; break;
        case 2:  feat = p2; H = 64;  break;
        case 3:  feat = p3; H = 32;  break;
        default: feat = p4; H = 16;  break;
    }
    float hf = (float)(H - 1);

    const float* b = det + di * DSTR;
    float bx1 = b[0], by1 = b[1], bx2 = b[2], by2 = b[3];

    float y1n = by1 / hf, y2n = by2 / hf;
    float x1n = bx1 / hf, x2n = bx2 / hf;   // W == H per level
    float ty = (float)py / 13.0f;
    float tx = (float)px / 13.0f;
    float ys = (y1n + (y2n - y1n) * ty) * hf;
    float xs = (x1n + (x2n - x1n) * tx) * hf;

    float4* outp = (float4*)(out + (size_t)(slot * NPIX + p) * C) + lane;

    bool valid = (ys >= 0.0f) & (ys <= hf) & (xs >= 0.0f) & (xs <= hf);
    if (!valid) {
        *outp = make_float4(0.0f, 0.0f, 0.0f, 0.0f);
        return;
    }

    float y0f = floorf(ys), x0f = floorf(xs);
    float ly = ys - y0f,    lx = xs - x0f;
    int y0i = (int)fminf(fmaxf(y0f,        0.0f), hf);
    int y1i = (int)fminf(fmaxf(y0f + 1.0f, 0.0f), hf);
    int x0i = (int)fminf(fmaxf(x0f,        0.0f), hf);
    int x1i = (int)fminf(fmaxf(x0f + 1.0f, 0.0f), hf);

    const float4* f00 = (const float4*)(feat + (size_t)(y0i * H + x0i) * C) + lane;
    const float4* f01 = (const float4*)(feat + (size_t)(y0i * H + x1i) * C) + lane;
    const float4* f10 = (const float4*)(feat + (size_t)(y1i * H + x0i) * C) + lane;
    const float4* f11 = (const float4*)(feat + (size_t)(y1i * H + x1i) * C) + lane;

    float4 a = *f00, c01 = *f01, d10 = *f10, e11 = *f11;
    float4 o;
    o.x = blerp(a.x, c01.x, d10.x, e11.x, lx, ly);
    o.y = blerp(a.y, c01.y, d10.y, e11.y, lx, ly);
    o.z = blerp(a.z, c01.z, d10.z, e11.z, lx, ly);
    o.w = blerp(a.w, c01.w, d10.w, e11.w, lx, ly);
    *outp = o;
}

extern "C" void kernel_launch(void* const* d_in, const int* in_sizes, int n_in,
                              void* d_out, int out_size, void* d_ws, size_t ws_size,
                              hipStream_t stream) {
    const float* det = (const float*)d_in[0];
    const float* p0  = (const float*)d_in[1];
    const float* p1  = (const float*)d_in[2];
    const float* p2  = (const float*)d_in[3];
    const float* p3  = (const float*)d_in[4];
    const float* p4  = (const float*)d_in[5];
    float* out = (float*)d_out;

    char* ws = (char*)d_ws;
    float* scores    = (float*)(ws + 0);          // 5000 floats
    int*   rank      = (int*)(ws + 20000);        // 5000 ints
    int*   topk_idx  = (int*)(ws + 40000);        // 1000 ints
    int*   slot_det  = (int*)(ws + 44000);        // 1000 ints
    int*   slot_lvl  = (int*)(ws + 48000);        // 1000 ints

    scores_kernel<<<(NDET + 255) / 256, 256, 0, stream>>>(det, scores, rank);
    dim3 rg((NDET + ICHUNK - 1) / ICHUNK, NDET / JCHUNK);
    rank_kernel<<<rg, ICHUNK, 0, stream>>>(scores, rank);
    scatter_kernel<<<(NDET + 255) / 256, 256, 0, stream>>>(rank, topk_idx);
    order_kernel<<<1, 1024, 0, stream>>>(det, topk_idx, slot_det, slot_lvl);
    crop_kernel<<<TOPK * (NPIX / 4), 256, 0, stream>>>(det, p0, p1, p2, p3, p4,
                                                       slot_det, slot_lvl, out);
}